// Round 7
// baseline (251.055 us; speedup 1.0000x reference)
//
#include <hip/hip_runtime.h>

#define HW    3136   // 56*56
#define HW4   784    // float4 per (b,c) row
#define C     512
#define B     32
#define ROWS  (B * C)        // 16384
#define RPB   8              // rows (channels) per block
#define NBLK  (ROWS / RPB)   // 2048 blocks -> 8 blocks/CU, ALL co-resident
#define BPB   (C / RPB)      // 64 blocks per batch

typedef float floatx4 __attribute__((ext_vector_type(4)));

// Single regular dispatch. Block i owns rows [8i, 8i+8): one batch b, one
// modality m (8-aligned run of 8 channels never crosses a 64-channel block).
// Cross-block dataflow is via device-scope atomics ONLY:
//   phase 1: 8 row-means -> LDS
//   8 threads: partial dot acc[b][m'] += sum_r mean[r]*W[m',c0+r]  (release)
//   barrier:  cnt[b] += 1 (release); thread 0 spins acquire until == 64
//   gate:     thread 0 acquire-loads acc[b][m], sigmoid(relu(+bias)), LDS bcast
//   phase 2:  scale own 8 rows; x re-read is L3-resident (round-5 FETCH proof);
//             nt stores keep the out stream from evicting x.
// launch_bounds(256,8) => VGPR<=64, LDS ~40B => 8 blocks/CU guaranteed =>
// entire 2048-block grid is resident; the spin barrier cannot deadlock.
__global__ __launch_bounds__(256, 8)
void se_fused_kernel(const float* __restrict__ x,
                     const float* __restrict__ W,
                     const float* __restrict__ bias,
                     float* __restrict__ acc,   // [B*8] floats, zeroed per call
                     int*   __restrict__ cnt,   // [B] ints, zeroed per call
                     float* __restrict__ out) {
    const int wave = threadIdx.x >> 6;
    const int lane = threadIdx.x & 63;
    const int row0 = blockIdx.x * RPB;
    const int b    = row0 >> 9;             // batch
    const int c0   = row0 & (C - 1);        // first channel (multiple of 8)
    const int m    = c0 >> 6;               // modality of all 8 rows

    __shared__ float means[RPB];
    __shared__ float sgate;

    // ---- phase 1: 8 row means (2 per wave) ----
    #pragma unroll
    for (int r = 0; r < 2; ++r) {
        const int row = row0 + wave * 2 + r;
        const floatx4* xr = reinterpret_cast<const floatx4*>(x) + (size_t)row * HW4;
        float s = 0.f;
        for (int i = lane; i < HW4; i += 64) {
            floatx4 v = xr[i];
            s += (v.x + v.y) + (v.z + v.w);
        }
        #pragma unroll
        for (int off = 32; off; off >>= 1) s += __shfl_down(s, off, 64);
        if (lane == 0) means[wave * 2 + r] = s * (1.0f / HW);
    }
    __syncthreads();

    // ---- partial gate dots: thread t<8 handles modality t ----
    if (threadIdx.x < 8) {
        const float* wr = W + threadIdx.x * C + c0;
        float p = 0.f;
        #pragma unroll
        for (int r = 0; r < RPB; ++r) p = fmaf(means[r], wr[r], p);
        __hip_atomic_fetch_add(&acc[b * 8 + threadIdx.x], p,
                               __ATOMIC_RELEASE, __HIP_MEMORY_SCOPE_AGENT);
    }
    __syncthreads();   // drains the 8 atomic adds (vmcnt) before arrival

    // ---- per-batch barrier + gate ----
    if (threadIdx.x == 0) {
        __hip_atomic_fetch_add(&cnt[b], 1, __ATOMIC_RELEASE, __HIP_MEMORY_SCOPE_AGENT);
        while (__hip_atomic_load(&cnt[b], __ATOMIC_ACQUIRE, __HIP_MEMORY_SCOPE_AGENT) < BPB)
            __builtin_amdgcn_s_sleep(2);
        float v = __hip_atomic_load(&acc[b * 8 + m],
                                    __ATOMIC_ACQUIRE, __HIP_MEMORY_SCOPE_AGENT);
        v += bias[m];
        v = fmaxf(v, 0.f);                     // relu
        sgate = 1.0f / (1.0f + expf(-v));      // sigmoid
    }
    __syncthreads();
    const float g = sgate;

    // ---- phase 2: scale own 8 rows (L3-warm reads), nt stores ----
    #pragma unroll
    for (int r = 0; r < 2; ++r) {
        const int row = row0 + wave * 2 + r;
        const floatx4* xr  = reinterpret_cast<const floatx4*>(x) + (size_t)row * HW4;
        floatx4*      orow = reinterpret_cast<floatx4*>(out)     + (size_t)row * HW4;
        for (int i = lane; i < HW4; i += 64) {
            floatx4 v = xr[i];
            v *= g;
            __builtin_nontemporal_store(v, &orow[i]);
        }
    }
}

extern "C" void kernel_launch(void* const* d_in, const int* in_sizes, int n_in,
                              void* d_out, int out_size, void* d_ws, size_t ws_size,
                              hipStream_t stream) {
    const float* x    = (const float*)d_in[0];  // (32,512,56,56)
    const float* W    = (const float*)d_in[1];  // (8,512)
    const float* bias = (const float*)d_in[2];  // (8,)
    float* out = (float*)d_out;

    float* acc = (float*)d_ws;                       // 256 floats @ offset 0
    int*   cnt = (int*)((char*)d_ws + 1024);         // 32 ints   @ offset 1024

    hipMemsetAsync(d_ws, 0, 1152, stream);           // zero acc + cnt each call

    se_fused_kernel<<<NBLK, 256, 0, stream>>>(x, W, bias, acc, cnt, out);
}

// Round 8
// 94.667 us; speedup vs baseline: 2.6520x; 2.6520x over previous
//
#include <hip/hip_runtime.h>

#define HW    3136   // 56*56
#define HW4   784    // float4 per (b,c) row = 12*64 + 16
#define C     512
#define B     32
#define ROWS  (B * C)   // 16384

typedef float floatx4 __attribute__((ext_vector_type(4)));

// Pass 1: one wave per (b,c) row. 12 independent unrolled dwordx4 loads +
// 16-lane tail, then butterfly reduce. Normal (caching) loads so x lands in
// L3 for the scale pass (round-5/7 FETCH proof: re-read is fully L3-served).
__global__ __launch_bounds__(256) void se_mean_kernel(const float* __restrict__ x,
                                                      float* __restrict__ y) {
    const int wave = threadIdx.x >> 6;
    const int lane = threadIdx.x & 63;
    const int row  = blockIdx.x * 4 + wave;   // [0, 16384)
    const floatx4* xr = reinterpret_cast<const floatx4*>(x) + (size_t)row * HW4;

    float s = 0.f;
    #pragma unroll
    for (int k = 0; k < 12; ++k) {            // 12*64 = 768 float4, uniform
        floatx4 v = xr[lane + 64 * k];
        s += (v.x + v.y) + (v.z + v.w);
    }
    if (lane < 16) {                          // float4 768..783
        floatx4 v = xr[768 + lane];
        s += (v.x + v.y) + (v.z + v.w);
    }
    #pragma unroll
    for (int off = 32; off; off >>= 1) s += __shfl_down(s, off, 64);
    if (lane == 0) y[row] = s * (1.0f / HW);
}

// Pass 2 (fused gate+scale): block owns 8 consecutive rows (one batch, one
// modality since 8 | 64). Gate computed redundantly per wave (no LDS/barrier).
// Reverse block order reads the L3-hottest tail of x first; nt stores keep
// the out stream from evicting x from Infinity Cache.
__global__ __launch_bounds__(256) void se_scale_kernel(const float* __restrict__ x,
                                                       const float* __restrict__ y,
                                                       const float* __restrict__ W,
                                                       const float* __restrict__ bias,
                                                       float* __restrict__ out) {
    const int row0 = (gridDim.x - 1 - blockIdx.x) * 8;  // reverse order
    const int b    = row0 >> 9;
    const int m    = (row0 & (C - 1)) >> 6;
    const int wave = threadIdx.x >> 6;
    const int lane = threadIdx.x & 63;

    // gate: 512-length dot, 8 FMA per lane, butterfly so every lane has it
    const float* yb = y + b * C;
    const float* wm = W + m * C;
    float s = 0.f;
    #pragma unroll
    for (int i = 0; i < 8; ++i) s = fmaf(yb[lane + 64 * i], wm[lane + 64 * i], s);
    #pragma unroll
    for (int off = 32; off; off >>= 1) s += __shfl_xor(s, off, 64);
    s += bias[m];
    s = fmaxf(s, 0.f);                          // relu
    const float g = 1.0f / (1.0f + expf(-s));   // sigmoid

    // scale 2 rows per wave, unrolled 12 + tail, nt stores
    #pragma unroll
    for (int r = 0; r < 2; ++r) {
        const int row = row0 + wave * 2 + r;
        const floatx4* xr  = reinterpret_cast<const floatx4*>(x) + (size_t)row * HW4;
        floatx4*      orow = reinterpret_cast<floatx4*>(out)     + (size_t)row * HW4;
        #pragma unroll
        for (int k = 0; k < 12; ++k) {
            floatx4 v = xr[lane + 64 * k];
            v *= g;
            __builtin_nontemporal_store(v, &orow[lane + 64 * k]);
        }
        if (lane < 16) {
            floatx4 v = xr[768 + lane];
            v *= g;
            __builtin_nontemporal_store(v, &orow[768 + lane]);
        }
    }
}

extern "C" void kernel_launch(void* const* d_in, const int* in_sizes, int n_in,
                              void* d_out, int out_size, void* d_ws, size_t ws_size,
                              hipStream_t stream) {
    const float* x    = (const float*)d_in[0];  // (32,512,56,56)
    const float* W    = (const float*)d_in[1];  // (8,512)
    const float* bias = (const float*)d_in[2];  // (8,)
    float* out = (float*)d_out;

    float* y = (float*)d_ws;                    // 16384 floats = 64 KB

    se_mean_kernel <<<ROWS / 4, 256, 0, stream>>>(x, y);
    se_scale_kernel<<<ROWS / 8, 256, 0, stream>>>(x, y, W, bias, out);
}